// Round 11
// baseline (770.614 us; speedup 1.0000x reference)
//
#include <hip/hip_runtime.h>

#define NB   16
#define NN   2048
#define NPTS (NB * NN)
#define KNB  6
#define MSUP 12          // exact-rescore superset size

typedef __attribute__((ext_vector_type(8))) short short8;
typedef __attribute__((ext_vector_type(4))) float f32x4;
typedef const __attribute__((address_space(4))) float cfloat;

// ---------------- squared-norm kernel (exact fp32) ----------------
template<int C>
__global__ void sq_kernel(const float* __restrict__ x, float* __restrict__ sq) {
    int i = blockIdx.x * blockDim.x + threadIdx.x;
    if (i >= NPTS) return;
    const float4* r = (const float4*)(x + (size_t)i * C);
    float s = 0.f;
#pragma unroll
    for (int c = 0; c < C / 4; ++c) {
        float4 f = r[c];
        s += f.x * f.x + f.y * f.y + f.z * f.z + f.w * f.w;
    }
    sq[i] = s;
}

// ---------------- split-precision prep: x -> bf16 hi + bf16 lo ----------------
__device__ __forceinline__ unsigned bf16_rne(float f) {
    unsigned u = __float_as_uint(f);
    return (u + 0x7fffu + ((u >> 16) & 1u)) >> 16;
}
template<int C>
__global__ void prep_x(const float* __restrict__ x,
                       unsigned short* __restrict__ Xhi,
                       unsigned short* __restrict__ Xlo) {
    int t = blockIdx.x * 256 + threadIdx.x;
    if (t >= NPTS * C) return;
    float f = x[t];
    unsigned h = bf16_rne(f);
    float hf = __uint_as_float(h << 16);
    unsigned l = bf16_rne(f - hf);
    Xhi[t] = (unsigned short)h;
    Xlo[t] = (unsigned short)l;
}

// ---------------- weight prep: transpose the three W1s ----------------
__global__ void prep_w(const float* __restrict__ W10, const float* __restrict__ W11,
                       const float* __restrict__ W12,
                       float* __restrict__ T0, float* __restrict__ T1,
                       float* __restrict__ T2) {
    int t = blockIdx.x * 256 + threadIdx.x;
    if (t < 4096) { int o = t >> 6, c = t & 63;  T0[o * 64 + c]  = W10[c * 64 + o]; }
    if (t < 4096) { int o = t >> 7, c = t & 127; T1[o * 128 + c] = W11[c * 32 + o]; }
    if (t < 4096) { int o = t >> 6, c = t & 63;  T2[o * 64 + c]  = W12[c * 64 + o]; }
}

// ---------------- MFMA kNN scan ----------------
// wave = 16 queries x 512 candidates (quarter sp). D via 16x16x32 bf16 MFMA,
// hi/lo split (hi*hi+hi*lo+lo*hi). Per-lane top-6 of its (sp,g) sublist kept
// as PACKED u32 keys: flip(score)[31:11] | idx[10:0] (2.4e-4 rel quantization
// affects only the superset pick; exact fp32 rescore follows). Sublists land
// in plist[z][k][q] (z=sp*4+g, 16 per query), coalesced for the merge.
// A-fragments double-buffered (global->reg prefetch). 8192 waves.
template<int C>
__global__ __launch_bounds__(256)
void knn_scan(const unsigned short* __restrict__ Xhi,
              const unsigned short* __restrict__ Xlo,
              const float* __restrict__ sqv,
              unsigned* __restrict__ plist) {
    constexpr int KT = C / 32;
    constexpr int NT = 512 / 16;            // tiles per quarter
    const int w    = __builtin_amdgcn_readfirstlane(threadIdx.x >> 6);
    const int W    = blockIdx.x * 4 + w;
    const int sp   = W & 3;                 // candidate quarter
    const int qt   = (W >> 2) & 127;        // query tile
    const int b    = W >> 9;                // batch
    const int lane = threadIdx.x & 63;
    const int n    = lane & 15;             // query within tile (D col)
    const int g    = lane >> 4;             // row group (D rows 4g..4g+3)
    const int base = b * NN;
    const int qloc = qt * 16 + n;           // batch-local query index

    // B fragments (queries), persistent
    short8 bh[KT], bl[KT];
#pragma unroll
    for (int kt = 0; kt < KT; ++kt) {
        const size_t off = (size_t)(base + qloc) * C + kt * 32 + g * 8;
        bh[kt] = *(const short8*)(Xhi + off);
        bl[kt] = *(const short8*)(Xlo + off);
    }

    unsigned dl[6];
#pragma unroll
    for (int k = 0; k < 6; ++k) dl[k] = 0xFFFFFFFFu;

    const int jbeg = sp * 512;

    // A fragments, double-buffered
    short8 ah[2][KT], al[2][KT];
#pragma unroll
    for (int kt = 0; kt < KT; ++kt) {
        const size_t off = (size_t)(base + jbeg + n) * C + kt * 32 + g * 8;
        ah[0][kt] = *(const short8*)(Xhi + off);
        al[0][kt] = *(const short8*)(Xlo + off);
    }

#pragma unroll 2
    for (int t = 0; t < NT; ++t) {
        const int jb  = jbeg + t * 16;
        const int cur = t & 1, nxt = cur ^ 1;
        if (t + 1 < NT) {
#pragma unroll
            for (int kt = 0; kt < KT; ++kt) {
                const size_t off = (size_t)(base + jb + 16 + n) * C + kt * 32 + g * 8;
                ah[nxt][kt] = *(const short8*)(Xhi + off);
                al[nxt][kt] = *(const short8*)(Xlo + off);
            }
        }
        f32x4 acc = {0.f, 0.f, 0.f, 0.f};
#pragma unroll
        for (int kt = 0; kt < KT; ++kt) {
            acc = __builtin_amdgcn_mfma_f32_16x16x32_bf16(ah[cur][kt], bh[kt], acc, 0, 0, 0);
            acc = __builtin_amdgcn_mfma_f32_16x16x32_bf16(ah[cur][kt], bl[kt], acc, 0, 0, 0);
            acc = __builtin_amdgcn_mfma_f32_16x16x32_bf16(al[cur][kt], bh[kt], acc, 0, 0, 0);
        }
        const float4 sq4 = *(const float4*)(sqv + base + jb + g * 4);
#pragma unroll
        for (int r = 0; r < 4; ++r) {
            const int jloc = jb + g * 4 + r;
            const float sc = fmaf(-2.f, acc[r],
                            r == 0 ? sq4.x : r == 1 ? sq4.y : r == 2 ? sq4.z : sq4.w);
            unsigned u = __float_as_uint(sc);
            u ^= (unsigned)((int)u >> 31) | 0x80000000u;          // sortable flip
            unsigned key = (u & 0xFFFFF800u) | (unsigned)jloc;    // score|idx
            key = (jloc == qloc) ? 0xFFFFFFFFu : key;             // self-exclude
#pragma unroll
            for (int k = 0; k < 6; ++k) {                         // branchless insert
                const unsigned ok = dl[k];
                const bool c = key < ok;
                dl[k] = c ? key : ok;
                key   = c ? ok  : key;
            }
        }
    }

    // plist[z][k][q], z = sp*4+g  (coalesced for merge)
    const int z = sp * 4 + g;
#pragma unroll
    for (int k = 0; k < 6; ++k)
        plist[(size_t)(z * 6 + k) * NPTS + (base + qloc)] = dl[k];
}

// ---------------- merge: 16 sorted 6-sublists -> top-12 superset ----------------
__global__ __launch_bounds__(256)
void knn_merge(const unsigned* __restrict__ plist, int* __restrict__ cidx) {
    const int q = blockIdx.x * 256 + threadIdx.x;
    if (q >= NPTS) return;

    // preload all 16 heads (independent loads -> one latency)
    unsigned head[16];
#pragma unroll
    for (int z = 0; z < 16; ++z) head[z] = plist[(size_t)(z * 6) * NPTS + q];

    unsigned best[MSUP];
#pragma unroll
    for (int k = 0; k < MSUP; ++k) best[k] = 0xFFFFFFFFu;

    for (int z = 0; z < 16; ++z) {
        unsigned v = head[z];
        for (int e = 0; e < 6; ++e) {
            if (e) v = plist[(size_t)(z * 6 + e) * NPTS + q];
            if (v >= best[MSUP - 1]) break;      // sublist ascending
            best[MSUP - 1] = v;
#pragma unroll
            for (int k = MSUP - 2; k >= 0; --k) {
                if (best[k + 1] < best[k]) {
                    unsigned t = best[k]; best[k] = best[k + 1]; best[k + 1] = t;
                }
            }
        }
    }
#pragma unroll
    for (int m = 0; m < MSUP; ++m)
        cidx[(size_t)m * NPTS + q] = (int)(best[m] & 2047u);
}

// ---------------- exact rescore: thread = (query, m) ----------------
template<int C>
__global__ __launch_bounds__(256)
void rescore_exact(const float* __restrict__ x, const float* __restrict__ sqv,
                   const int* __restrict__ cidx, unsigned long long* __restrict__ keys) {
    const int t = blockIdx.x * 256 + threadIdx.x;
    const int q = t & (NPTS - 1);
    const int m = t >> 15;
    const int base = q & ~(NN - 1);
    const int jloc = cidx[(size_t)m * NPTS + q];

    const float4* qp = (const float4*)(x + (size_t)q * C);
    const float4* cp = (const float4*)(x + (size_t)(base + jloc) * C);
    float d0 = 0.f, d1 = 0.f, d2 = 0.f, d3 = 0.f;
#pragma unroll
    for (int c4 = 0; c4 < C / 4; ++c4) {
        float4 a = cp[c4], qv = qp[c4];
        d0 = fmaf(a.x, qv.x, d0);
        d1 = fmaf(a.y, qv.y, d1);
        d2 = fmaf(a.z, qv.z, d2);
        d3 = fmaf(a.w, qv.w, d3);
    }
    const float s = fmaf(-2.f, (d0 + d1) + (d2 + d3), sqv[base + jloc]);
    unsigned u = __float_as_uint(s);
    u ^= (unsigned)((int)u >> 31) | 0x80000000u;
    keys[(size_t)m * NPTS + q] = ((unsigned long long)u << 11) | (unsigned)jloc;
}

// ---------------- pick: exact top-6 from the 12 exact keys ----------------
__global__ __launch_bounds__(256)
void knn_pick(const unsigned long long* __restrict__ keys, int* __restrict__ nbr) {
    const int q = blockIdx.x * 256 + threadIdx.x;
    if (q >= NPTS) return;
    const int base = q & ~(NN - 1);
    unsigned long long out6[6];
#pragma unroll
    for (int k = 0; k < 6; ++k) out6[k] = ~0ull;
    for (int m = 0; m < MSUP; ++m) {
        unsigned long long key = keys[(size_t)m * NPTS + q];
#pragma unroll
        for (int k = 0; k < 6; ++k) {
            const unsigned long long ok = out6[k];
            const bool c = key < ok;
            out6[k] = c ? key : ok;
            key     = c ? ok  : key;
        }
    }
#pragma unroll
    for (int k = 0; k < 6; ++k)
        nbr[q * KNB + k] = base + (int)(out6[k] & 2047ull);
}

// ---------------- edge MLP kernel ----------------
// block = 384 thr = 6 waves; lane = point; wave = neighbor. Weight streams
// via address_space(4) uniform loads (scalar pipe); 6->1 max via LDS tree.
template<int CIN, int COUT, bool RESID, int MINW>
__global__ __launch_bounds__(384, MINW)
void mlp_kernel(const float* __restrict__ xin, const int* __restrict__ nbr,
                const float* __restrict__ W1T, const float* __restrict__ b1,
                const float* __restrict__ W2,  const float* __restrict__ b2,
                const float* __restrict__ resid, float* __restrict__ out) {
    constexpr int RS = COUT + 4;
    __shared__ float Buf[3][64][RS];

    const int lane = threadIdx.x & 63;
    const int w    = __builtin_amdgcn_readfirstlane(threadIdx.x >> 6);  // 0..5
    const int i    = blockIdx.x * 64 + lane;

    float xi[CIN], xd[CIN];
    {
        const float* xp = xin + (size_t)i * CIN;
#pragma unroll
        for (int c = 0; c < CIN; c += 4) {
            float4 f = *(const float4*)(xp + c);
            xi[c] = f.x; xi[c + 1] = f.y; xi[c + 2] = f.z; xi[c + 3] = f.w;
        }
        const int j = nbr[i * KNB + w];
        const float* jp = xin + (size_t)j * CIN;
#pragma unroll
        for (int c = 0; c < CIN; c += 4) {
            float4 f = *(const float4*)(jp + c);
            xd[c]     = f.x - xi[c];     xd[c + 1] = f.y - xi[c + 1];
            xd[c + 2] = f.z - xi[c + 2]; xd[c + 3] = f.w - xi[c + 3];
        }
    }

    float uacc[COUT];
#pragma unroll
    for (int o = 0; o < COUT; ++o) uacc[o] = 0.f;

    cfloat* W1c = (cfloat*)(uintptr_t)W1T;
    cfloat* b1c = (cfloat*)(uintptr_t)b1;
    cfloat* W2c = (cfloat*)(uintptr_t)W2;

    for (int op = 0; op < COUT; ++op) {
        cfloat* w1r = W1c + (size_t)op * (2 * CIN);
        float h0 = 0.f, h1 = 0.f, h2 = 0.f, h3 = 0.f;
#pragma unroll
        for (int c = 0; c < CIN; c += 4) {
            h0 = fmaf(w1r[c],     xi[c],     h0);
            h1 = fmaf(w1r[c + 1], xi[c + 1], h1);
            h2 = fmaf(w1r[c + 2], xi[c + 2], h2);
            h3 = fmaf(w1r[c + 3], xi[c + 3], h3);
        }
#pragma unroll
        for (int c = 0; c < CIN; c += 4) {
            h0 = fmaf(w1r[CIN + c],     xd[c],     h0);
            h1 = fmaf(w1r[CIN + c + 1], xd[c + 1], h1);
            h2 = fmaf(w1r[CIN + c + 2], xd[c + 2], h2);
            h3 = fmaf(w1r[CIN + c + 3], xd[c + 3], h3);
        }
        const float h = fmaxf((h0 + h1) + (h2 + h3) + b1c[op], 0.f);
        cfloat* w2r = W2c + (size_t)op * COUT;
#pragma unroll
        for (int o = 0; o < COUT; ++o)
            uacc[o] = fmaf(w2r[o], h, uacc[o]);
    }

    if (w >= 3) {
#pragma unroll
        for (int o = 0; o < COUT; ++o) Buf[w - 3][lane][o] = uacc[o];
    }
    __syncthreads();
    if (w < 3) {
#pragma unroll
        for (int o = 0; o < COUT; ++o) uacc[o] = fmaxf(uacc[o], Buf[w][lane][o]);
    }
    __syncthreads();
    if (w == 1 || w == 2) {
#pragma unroll
        for (int o = 0; o < COUT; ++o) Buf[w][lane][o] = uacc[o];
    }
    __syncthreads();
    if (w == 0) {
        float* po = out + (size_t)i * COUT;
#pragma unroll
        for (int o = 0; o < COUT; ++o) {
            float v = fmaxf(uacc[o], fmaxf(Buf[1][lane][o], Buf[2][lane][o])) + b2[o];
            if (RESID) v += resid[(size_t)i * COUT + o];
            po[o] = fmaxf(v, 0.f);
        }
    }
}

extern "C" void kernel_launch(void* const* d_in, const int* in_sizes, int n_in,
                              void* d_out, int out_size, void* d_ws, size_t ws_size,
                              hipStream_t stream) {
    const float* x    = (const float*)d_in[0];
    const float* W1_0 = (const float*)d_in[2];
    const float* b1_0 = (const float*)d_in[3];
    const float* W2_0 = (const float*)d_in[4];
    const float* b2_0 = (const float*)d_in[5];
    const float* W1_1 = (const float*)d_in[6];
    const float* b1_1 = (const float*)d_in[7];
    const float* W2_1 = (const float*)d_in[8];
    const float* b2_1 = (const float*)d_in[9];
    const float* W1_2 = (const float*)d_in[10];
    const float* b1_2 = (const float*)d_in[11];
    const float* W2_2 = (const float*)d_in[12];
    const float* b2_2 = (const float*)d_in[13];
    float* outp = (float*)d_out;

    // workspace layout (8B-aligned blocks first)
    unsigned long long* keys = (unsigned long long*)d_ws;          // MSUP*NPTS u64
    unsigned* plist = (unsigned*)(keys + (size_t)MSUP * NPTS);     // 16*6*NPTS u32
    int* cidx = (int*)(plist + (size_t)96 * NPTS);                 // MSUP*NPTS
    float* x0  = (float*)(cidx + (size_t)MSUP * NPTS);             // 32768 x 64
    float* x1  = x0 + (size_t)NPTS * 64;                           // 32768 x 32
    float* sqb = x1 + (size_t)NPTS * 32;                           // 32768
    float* T0  = sqb + NPTS;                                       // 64 x 64
    float* T1  = T0 + 4096;                                        // 32 x 128
    float* T2  = T1 + 4096;                                        // 64 x 64
    unsigned short* Xhi = (unsigned short*)(T2 + 4096);            // 32768 x 64 u16
    unsigned short* Xlo = Xhi + (size_t)NPTS * 64;                 // 32768 x 64 u16
    int* nbr = (int*)(Xlo + (size_t)NPTS * 64);                    // 32768 x 6

    const int sgrid  = NPTS / 256;          // 128
    const int scgrid = 2048;                // 8192 waves
    const int rgrid  = NPTS * MSUP / 256;   // 1536
    const int pgrid  = NPTS / 64;

    prep_w<<<16, 256, 0, stream>>>(W1_0, W1_1, W1_2, T0, T1, T2);

    // ---- layer 0: x (32) -> x0 (64), relu ----
    sq_kernel<32><<<sgrid, 256, 0, stream>>>(x, sqb);
    prep_x<32><<<NPTS * 32 / 256, 256, 0, stream>>>(x, Xhi, Xlo);
    knn_scan<32><<<scgrid, 256, 0, stream>>>(Xhi, Xlo, sqb, plist);
    knn_merge<<<sgrid, 256, 0, stream>>>(plist, cidx);
    rescore_exact<32><<<rgrid, 256, 0, stream>>>(x, sqb, cidx, keys);
    knn_pick<<<sgrid, 256, 0, stream>>>(keys, nbr);
    mlp_kernel<32, 64, false, 3><<<pgrid, 384, 0, stream>>>(x, nbr, T0, b1_0, W2_0, b2_0, nullptr, x0);

    // ---- layer 1: x0 (64) -> x1 (32), relu ----
    sq_kernel<64><<<sgrid, 256, 0, stream>>>(x0, sqb);
    prep_x<64><<<NPTS * 64 / 256, 256, 0, stream>>>(x0, Xhi, Xlo);
    knn_scan<64><<<scgrid, 256, 0, stream>>>(Xhi, Xlo, sqb, plist);
    knn_merge<<<sgrid, 256, 0, stream>>>(plist, cidx);
    rescore_exact<64><<<rgrid, 256, 0, stream>>>(x0, sqb, cidx, keys);
    knn_pick<<<sgrid, 256, 0, stream>>>(keys, nbr);
    mlp_kernel<64, 32, false, 2><<<pgrid, 384, 0, stream>>>(x0, nbr, T1, b1_1, W2_1, b2_1, nullptr, x1);

    // ---- layer 2: x1 (32) -> out (64), +x0 residual, relu ----
    sq_kernel<32><<<sgrid, 256, 0, stream>>>(x1, sqb);
    prep_x<32><<<NPTS * 32 / 256, 256, 0, stream>>>(x1, Xhi, Xlo);
    knn_scan<32><<<scgrid, 256, 0, stream>>>(Xhi, Xlo, sqb, plist);
    knn_merge<<<sgrid, 256, 0, stream>>>(plist, cidx);
    rescore_exact<32><<<rgrid, 256, 0, stream>>>(x1, sqb, cidx, keys);
    knn_pick<<<sgrid, 256, 0, stream>>>(keys, nbr);
    mlp_kernel<32, 64, true, 3><<<pgrid, 384, 0, stream>>>(x1, nbr, T2, b1_2, W2_2, b2_2, x0, outp);
}